// Round 15
// baseline (152.806 us; speedup 1.0000x reference)
//
#include <hip/hip_runtime.h>
#include <hip/hip_bf16.h>
#include <math.h>

#define B_DIM 4
#define C_DIM 512
#define T_DIM 2048
#define H_DIM 8
#define OC3   1536
#define VN_STRIDE 2064   // R8-measured-best (R10 de-alias experiment regressed)
#define SCALE 0.044194173824159216f   // 512^-0.5 (full C, per reference)
#define SCALE2 (0.044194173824159216f * 1.4426950408889634f)   // fold log2(e)

typedef unsigned short ushortT;
typedef unsigned int uintT;
typedef __attribute__((ext_vector_type(8))) short bf16x8;
typedef __attribute__((ext_vector_type(4))) short bf16x4;
typedef __attribute__((ext_vector_type(4))) float f32x4;

__device__ __forceinline__ ushortT f2bf(float f) {
    union { float f; uintT u; } v; v.f = f;
    uintT r = v.u + 0x7FFF + ((v.u >> 16) & 1);   // RNE
    return (ushortT)(r >> 16);
}
__device__ __forceinline__ float bf2f(ushortT h) {
    union { uintT u; float f; } v; v.u = ((uintT)h) << 16;
    return v.f;
}
__device__ __forceinline__ uintT pack2bf(float a, float b) {
    uintT ua = __float_as_uint(a) + 0x8000u;
    uintT ub = __float_as_uint(b) + 0x8000u;
    return (ua >> 16) | (ub & 0xFFFF0000u);
}
// native pair conversion: compiler lowers adjacent __bf16 casts to
// v_cvt_pk_bf16_f32 on gfx950 (per m240: prefer casts over inline asm)
__device__ __forceinline__ uintT cvtpk2bf(float a, float b) {
    union { __bf16 v[2]; uintT u; } c;
    c.v[0] = (__bf16)a; c.v[1] = (__bf16)b;
    return c.u;
}
// async global->LDS, 16B per lane; lds base must be wave-uniform (data lands
// at base + lane*16) [m97/m104]
__device__ __forceinline__ void gload_lds16(const ushortT* g, ushortT* l) {
    __builtin_amdgcn_global_load_lds(
        (const __attribute__((address_space(1))) void*)g,
        (__attribute__((address_space(3))) void*)l, 16, 0, 0);
}

// ---------------------------------------------------------------------------
// prep: fused conv_x (blocks 0..1023) + conv_w (blocks 1024..2047).
// ---------------------------------------------------------------------------
__global__ __launch_bounds__(256) void prep(const float* __restrict__ x,
                                            const float* __restrict__ qw,
                                            const float* __restrict__ pw,
                                            ushortT* __restrict__ xb,
                                            ushortT* __restrict__ qwb,
                                            ushortT* __restrict__ pwb) {
    __shared__ float xs[64][65];
    const int tid = threadIdx.x;
    const int blk = blockIdx.x;
    if (blk >= 1024) {
        int idx = ((blk - 1024) * 256 + tid) * 4;
        if (idx < OC3 * C_DIM) {
            float4 v = *(const float4*)(qw + idx);
            qwb[idx + 0] = f2bf(v.x); qwb[idx + 1] = f2bf(v.y);
            qwb[idx + 2] = f2bf(v.z); qwb[idx + 3] = f2bf(v.w);
        } else {
            idx -= OC3 * C_DIM;
            float4 v = *(const float4*)(pw + idx);
            pwb[idx + 0] = f2bf(v.x); pwb[idx + 1] = f2bf(v.y);
            pwb[idx + 2] = f2bf(v.z); pwb[idx + 3] = f2bf(v.w);
        }
        return;
    }
    const int b = blk >> 8, rem = blk & 255;
    const int c0 = (rem >> 5) * 64, t0 = (rem & 31) * 64;
    #pragma unroll
    for (int it = 0; it < 4; ++it) {
        int idx = it * 256 + tid;
        int r = idx >> 4, ch = idx & 15;
        float4 v = *(const float4*)(x + ((size_t)(b * C_DIM + c0 + r)) * T_DIM + t0 + ch * 4);
        xs[r][ch * 4 + 0] = v.x; xs[r][ch * 4 + 1] = v.y;
        xs[r][ch * 4 + 2] = v.z; xs[r][ch * 4 + 3] = v.w;
    }
    __syncthreads();
    #pragma unroll
    for (int it = 0; it < 2; ++it) {
        int idx = it * 256 + tid;
        int rt = idx >> 3, ch = idx & 7;
        union { ushortT s[8]; uint4 v; } tmp;
        #pragma unroll
        for (int k = 0; k < 8; ++k) tmp.s[k] = f2bf(xs[ch * 8 + k][rt]);
        *(uint4*)(xb + ((size_t)b * T_DIM + t0 + rt) * C_DIM + c0 + ch * 8) = tmp.v;
    }
}

// ---------------------------------------------------------------------------
// QKV GEMM. R18 exact (verified best). Dispatch order already shares the
// B-panel across 64 consecutive blocks; R23's XCD swizzle regressed.
// ---------------------------------------------------------------------------
__global__ __launch_bounds__(256, 3) void gemm_qkv(const ushortT* __restrict__ A,
                                                   const ushortT* __restrict__ Bw,
                                                   const float* __restrict__ bias,
                                                   ushortT* __restrict__ out,
                                                   ushortT* __restrict__ Vn) {
    __shared__ __align__(16) ushortT As[8192], Bs[8192];   // 2 x [128][32] linear
    const int tid = threadIdx.x, lane = tid & 63, wid = tid >> 6;
    const int u = lane & 15, q = lane >> 4;
    const int wm = wid & 1, wn = wid >> 1;
    const int m0 = blockIdx.x * 128, n0 = blockIdx.y * 128;
    const int lrow = lane >> 2, lcol = (lane & 3) * 8;

    f32x4 acc[4][4];
    const f32x4 z = {0.f, 0.f, 0.f, 0.f};
    #pragma unroll
    for (int mi = 0; mi < 4; ++mi)
        #pragma unroll
        for (int ni = 0; ni < 4; ++ni) acc[mi][ni] = z;

    for (int k0 = 0; k0 < 512; k0 += 64) {
        __syncthreads();   // prior reads done before overwrite
        gload_lds16(A  + (size_t)(m0 + wid * 32 +      lrow) * 512 + k0      + lcol, &As[(wid * 32     ) * 32]);
        gload_lds16(A  + (size_t)(m0 + wid * 32 + 16 + lrow) * 512 + k0      + lcol, &As[(wid * 32 + 16) * 32]);
        gload_lds16(A  + (size_t)(m0 + wid * 32 +      lrow) * 512 + k0 + 32 + lcol, &As[4096 + (wid * 32     ) * 32]);
        gload_lds16(A  + (size_t)(m0 + wid * 32 + 16 + lrow) * 512 + k0 + 32 + lcol, &As[4096 + (wid * 32 + 16) * 32]);
        gload_lds16(Bw + (size_t)(n0 + wid * 32 +      lrow) * 512 + k0      + lcol, &Bs[(wid * 32     ) * 32]);
        gload_lds16(Bw + (size_t)(n0 + wid * 32 + 16 + lrow) * 512 + k0      + lcol, &Bs[(wid * 32 + 16) * 32]);
        gload_lds16(Bw + (size_t)(n0 + wid * 32 +      lrow) * 512 + k0 + 32 + lcol, &Bs[4096 + (wid * 32     ) * 32]);
        gload_lds16(Bw + (size_t)(n0 + wid * 32 + 16 + lrow) * 512 + k0 + 32 + lcol, &Bs[4096 + (wid * 32 + 16) * 32]);
        __syncthreads();   // vmcnt drained by barrier -> data visible
        bf16x8 af[4][2], bfr[4][2];
        #pragma unroll
        for (int mi = 0; mi < 4; ++mi) {
            af[mi][0] = *(const bf16x8*)&As[(wm * 64 + mi * 16 + u) * 32 + q * 8];
            af[mi][1] = *(const bf16x8*)&As[4096 + (wm * 64 + mi * 16 + u) * 32 + q * 8];
        }
        #pragma unroll
        for (int ni = 0; ni < 4; ++ni) {
            bfr[ni][0] = *(const bf16x8*)&Bs[(wn * 64 + ni * 16 + u) * 32 + q * 8];
            bfr[ni][1] = *(const bf16x8*)&Bs[4096 + (wn * 64 + ni * 16 + u) * 32 + q * 8];
        }
        #pragma unroll
        for (int mi = 0; mi < 4; ++mi)
            #pragma unroll
            for (int ni = 0; ni < 4; ++ni) {
                acc[mi][ni] = __builtin_amdgcn_mfma_f32_16x16x32_bf16(
                    af[mi][0], bfr[ni][0], acc[mi][ni], 0, 0, 0);
                acc[mi][ni] = __builtin_amdgcn_mfma_f32_16x16x32_bf16(
                    af[mi][1], bfr[ni][1], acc[mi][ni], 0, 0, 0);
            }
    }
    if (n0 < 1024) {   // Q or K region -> qkvT natural [m][o]
        const float scl = (n0 < 512) ? SCALE2 : 1.0f;
        #pragma unroll
        for (int ni = 0; ni < 4; ++ni) {
            int o = n0 + wn * 64 + ni * 16 + u;
            float bv = bias[o];
            #pragma unroll
            for (int mi = 0; mi < 4; ++mi)
                #pragma unroll
                for (int r = 0; r < 4; ++r) {
                    int m = m0 + wm * 64 + mi * 16 + q * 4 + r;
                    out[(size_t)m * OC3 + o] = f2bf((acc[mi][ni][r] + bv) * scl);
                }
        }
    } else {           // V region -> Vn[b][h][d][t] (transposed), packed 8B
        #pragma unroll
        for (int ni = 0; ni < 4; ++ni) {
            int o = n0 + wn * 64 + ni * 16 + u;
            float bv = bias[o];
            int oo = o - 1024;
            int hv = oo >> 6, d = oo & 63;
            #pragma unroll
            for (int mi = 0; mi < 4; ++mi) {
                int m = m0 + wm * 64 + mi * 16 + q * 4;
                int b = m >> 11, t = m & 2047;
                uint2 w;
                w.x = pack2bf(acc[mi][ni][0] + bv, acc[mi][ni][1] + bv);
                w.y = pack2bf(acc[mi][ni][2] + bv, acc[mi][ni][3] + bv);
                *(uint2*)(Vn + ((size_t)((b * 8 + hv) * 64 + d)) * VN_STRIDE + t) = w;
            }
        }
    }
}

// ---------------------------------------------------------------------------
// Flash attention: R24 (53.5 -> 51.8 us measured) with R25 tweak: setprio(1)
// window extended to cover the ka/va LDS fragment reads, not just the MFMA
// cluster -- the compute-phase wave also wins LDS arbitration against the
// co-resident block's staging phase (same inter-block mechanism as the
// measured +4.8% setprio win). Everything else byte-identical.
// CLOSED dead ends (do not retry): R11/R19/R21 occupancy-raising variants
// (spill / LDS-read amplification / spill), R12 manual K-dbuf, R16 small
// blocks, R17 gemm dbuf, R20 counted-vmcnt (drain is not the cost).
// ---------------------------------------------------------------------------
__global__ __launch_bounds__(256, 2)
void flash(const ushortT* __restrict__ qkvT, const ushortT* __restrict__ Vn,
           ushortT* __restrict__ AO)
{
    __shared__ __align__(16) ushortT smem[16384];   // K dbuf 2x8KB | V dbuf 2x8KB

    const int tid = threadIdx.x, lane = tid & 63, wid = tid >> 6;
    const int u = lane & 15, q = lane >> 4;
    const int g = blockIdx.x;
    const int bh = (g & 7) * 4 + ((g >> 3) & 3);   // 4 bh per XCD -> KV L2-resident
    const int qt = g >> 5;                         // 16 q-tiles per bh share L2 KV
    const int bb = bh >> 3, h = bh & 7;
    const int q0 = qt * 128;
    const size_t qbase = (size_t)bb * T_DIM * OC3;

    // Q: 32 rows per wave (2 sub-tiles of 16), register-resident
    bf16x8 qb[2][2];
    #pragma unroll
    for (int ti = 0; ti < 2; ++ti)
        #pragma unroll
        for (int kst = 0; kst < 2; ++kst)
            qb[ti][kst] = *(const bf16x8*)(qkvT + qbase
                + (size_t)(q0 + wid * 32 + ti * 16 + u) * OC3 + h * 64 + kst * 32 + q * 8);

    // staging source pointers: lane stages 16B that lands (linearly) at LDS
    // row rs, slot (lane&7); source column slot pre-swizzled: sg = s ^ (rs&7)
    const int rs = wid * 8 + (lane >> 3);            // tile row 0..31 (call0)
    const int sg = (lane & 7) ^ (rs & 7);            // (rs+32)&7 == rs&7
    const ushortT* ks0 = qkvT + qbase + (size_t)(rs     ) * OC3 + 512 + h * 64 + sg * 8;
    const ushortT* ks1 = qkvT + qbase + (size_t)(rs + 32) * OC3 + 512 + h * 64 + sg * 8;
    const ushortT* vs0 = Vn + ((size_t)bh * 64 + rs     ) * VN_STRIDE + sg * 8;
    const ushortT* vs1 = Vn + ((size_t)bh * 64 + rs + 32) * VN_STRIDE + sg * 8;

    f32x4 acc[4][2];
    const f32x4 z = {0.f, 0.f, 0.f, 0.f};
    #pragma unroll
    for (int ci = 0; ci < 4; ++ci)
        #pragma unroll
        for (int ti = 0; ti < 2; ++ti) acc[ci][ti] = z;
    f32x4 lacc[2] = {z, z};
    const bf16x4 ones = {(short)0x3F80, (short)0x3F80, (short)0x3F80, (short)0x3F80};

    // prologue: stage tile 0 into buf 0
    gload_lds16(ks0, &smem[       wid * 512]);
    gload_lds16(ks1, &smem[2048 + wid * 512]);
    gload_lds16(vs0, &smem[8192 +        wid * 512]);
    gload_lds16(vs1, &smem[8192 + 2048 + wid * 512]);
    ks0 += 64 * OC3; ks1 += 64 * OC3; vs0 += 64; vs1 += 64;
    __syncthreads();   // compiler drains vmcnt before barrier

    int cur = 0;
    for (int rnd = 0; rnd < 32; ++rnd) {
        if (rnd < 31) {   // prefetch next tile into other buffer (async)
            int nb = cur ^ 1;
            gload_lds16(ks0, &smem[nb * 4096 +        wid * 512]);
            gload_lds16(ks1, &smem[nb * 4096 + 2048 + wid * 512]);
            gload_lds16(vs0, &smem[8192 + nb * 4096 +        wid * 512]);
            gload_lds16(vs1, &smem[8192 + nb * 4096 + 2048 + wid * 512]);
            ks0 += 64 * OC3; ks1 += 64 * OC3; vs0 += 64; vs1 += 64;
        }
        const ushortT* Kb = &smem[cur * 4096];
        const ushortT* Vb = &smem[8192 + cur * 4096];
        __builtin_amdgcn_s_setprio(1);   // T5: cover LDS reads + MFMA cluster
        bf16x8 ka[4][2];
        #pragma unroll
        for (int si = 0; si < 4; ++si)
            #pragma unroll
            for (int kst = 0; kst < 2; ++kst)
                ka[si][kst] = *(const bf16x8*)&Kb[(si * 16 + u) * 64
                    + (((kst * 4 + q) ^ (u & 7)) * 8)];
        bf16x4 va[4][4];
        #pragma unroll
        for (int si = 0; si < 4; ++si)
            #pragma unroll
            for (int ci = 0; ci < 4; ++ci)
                va[si][ci] = *(const bf16x4*)&Vb[(ci * 16 + u) * 64
                    + (((si * 2 + (q >> 1)) ^ (u & 7)) * 8) + (q & 1) * 4];

        #pragma unroll
        for (int si = 0; si < 4; ++si) {
            f32x4 sacc[2] = {z, z};
            #pragma unroll
            for (int ti = 0; ti < 2; ++ti)
                sacc[ti] = __builtin_amdgcn_mfma_f32_16x16x32_bf16(
                    ka[si][0], qb[ti][0], sacc[ti], 0, 0, 0);
            #pragma unroll
            for (int ti = 0; ti < 2; ++ti)
                sacc[ti] = __builtin_amdgcn_mfma_f32_16x16x32_bf16(
                    ka[si][1], qb[ti][1], sacc[ti], 0, 0, 0);
            #pragma unroll
            for (int ti = 0; ti < 2; ++ti) {
                float p0 = __builtin_amdgcn_exp2f(sacc[ti][0]);
                float p1 = __builtin_amdgcn_exp2f(sacc[ti][1]);
                float p2 = __builtin_amdgcn_exp2f(sacc[ti][2]);
                float p3 = __builtin_amdgcn_exp2f(sacc[ti][3]);
                union { uint2 u2; bf16x4 v; } pw;
                pw.u2.x = cvtpk2bf(p0, p1);
                pw.u2.y = cvtpk2bf(p2, p3);
                lacc[ti] = __builtin_amdgcn_mfma_f32_16x16x16bf16_1k(
                    ones, pw.v, lacc[ti], 0, 0, 0);
                #pragma unroll
                for (int ci = 0; ci < 4; ++ci)
                    acc[ci][ti] = __builtin_amdgcn_mfma_f32_16x16x16bf16_1k(
                        va[si][ci], pw.v, acc[ci][ti], 0, 0, 0);
            }
        }
        __builtin_amdgcn_s_setprio(0);
        __syncthreads();   // next buffer staged + all reads of cur done
        cur ^= 1;
    }

    // ---- epilogue: reuse smem (all waves past final barrier) ----
    // Ob per wave: [32 q][72 d-pad] bf16; Lb: 4x32 f32 at ushort 9216
    ushortT* Ob = smem + wid * 2304;
    float* Lb = (float*)(smem + 9216);
    if (q == 0) {
        Lb[wid * 32 + u]      = lacc[0][0];
        Lb[wid * 32 + 16 + u] = lacc[1][0];
    }
    #pragma unroll
    for (int ci = 0; ci < 4; ++ci)
        #pragma unroll
        for (int ti = 0; ti < 2; ++ti) {
            uint2 w;
            w.x = pack2bf(acc[ci][ti][0], acc[ci][ti][1]);
            w.y = pack2bf(acc[ci][ti][2], acc[ci][ti][3]);
            *(uint2*)&Ob[(ti * 16 + u) * 72 + ci * 16 + q * 4] = w;
        }
    __syncthreads();
    {
        const int row = tid >> 1, cs = (tid & 1) * 32;   // 128 rows x 2 halves
        const int w = row >> 5, r32 = row & 31;
        float linv = 1.0f / Lb[w * 32 + r32];
        const ushortT* rp = smem + w * 2304 + r32 * 72 + cs;
        size_t orow = ((size_t)bb * T_DIM + q0 + row) * C_DIM + h * 64 + cs;
        #pragma unroll
        for (int j = 0; j < 4; ++j) {
            uint4 rv = *(const uint4*)(rp + j * 8);
            const uintT* rpp = (const uintT*)&rv;
            uint4 o;
            uintT* op = (uintT*)&o;
            #pragma unroll
            for (int k = 0; k < 4; ++k)
                op[k] = pack2bf(bf2f((ushortT)(rpp[k] & 0xFFFF)) * linv,
                                bf2f((ushortT)(rpp[k] >> 16)) * linv);
            *(uint4*)(AO + orow + j * 8) = o;
        }
    }
}

// ---------------------------------------------------------------------------
// Proj GEMM. R18 exact (verified best): 2-barrier, BN=64 -> grid 512 = 2/CU.
// out = Wp·AO^T + bias + x (fp32 out).
// ---------------------------------------------------------------------------
__global__ __launch_bounds__(256, 2) void gemm_proj(const ushortT* __restrict__ Wp,
                                                    const ushortT* __restrict__ AOv,
                                                    const float* __restrict__ bias,
                                                    const float* __restrict__ xres,
                                                    float* __restrict__ out) {
    __shared__ __align__(16) ushortT As[8192], Bs[4096];   // A: 2x[128][32]; B: 2x[64][32]
    const int tid = threadIdx.x, lane = tid & 63, wid = tid >> 6;
    const int u = lane & 15, q = lane >> 4;
    const int wm = wid & 1, wn = wid >> 1;
    const int m0 = blockIdx.y * 128, n0 = blockIdx.x * 64;
    const int lrow = lane >> 2, lcol = (lane & 3) * 8;

    f32x4 acc[4][2];
    const f32x4 z = {0.f, 0.f, 0.f, 0.f};
    #pragma unroll
    for (int mi = 0; mi < 4; ++mi)
        #pragma unroll
        for (int ni = 0; ni < 2; ++ni) acc[mi][ni] = z;

    for (int k0 = 0; k0 < 512; k0 += 64) {
        __syncthreads();
        gload_lds16(Wp  + (size_t)(m0 + wid * 32 +      lrow) * 512 + k0      + lcol, &As[(wid * 32     ) * 32]);
        gload_lds16(Wp  + (size_t)(m0 + wid * 32 + 16 + lrow) * 512 + k0      + lcol, &As[(wid * 32 + 16) * 32]);
        gload_lds16(Wp  + (size_t)(m0 + wid * 32 +      lrow) * 512 + k0 + 32 + lcol, &As[4096 + (wid * 32     ) * 32]);
        gload_lds16(Wp  + (size_t)(m0 + wid * 32 + 16 + lrow) * 512 + k0 + 32 + lcol, &As[4096 + (wid * 32 + 16) * 32]);
        gload_lds16(AOv + (size_t)(n0 + wid * 16 + lrow) * 512 + k0      + lcol, &Bs[(wid * 16) * 32]);
        gload_lds16(AOv + (size_t)(n0 + wid * 16 + lrow) * 512 + k0 + 32 + lcol, &Bs[2048 + (wid * 16) * 32]);
        __syncthreads();
        bf16x8 af[4][2], bfr[2][2];
        #pragma unroll
        for (int mi = 0; mi < 4; ++mi) {
            af[mi][0] = *(const bf16x8*)&As[(wm * 64 + mi * 16 + u) * 32 + q * 8];
            af[mi][1] = *(const bf16x8*)&As[4096 + (wm * 64 + mi * 16 + u) * 32 + q * 8];
        }
        #pragma unroll
        for (int ni = 0; ni < 2; ++ni) {
            bfr[ni][0] = *(const bf16x8*)&Bs[(wn * 32 + ni * 16 + u) * 32 + q * 8];
            bfr[ni][1] = *(const bf16x8*)&Bs[2048 + (wn * 32 + ni * 16 + u) * 32 + q * 8];
        }
        #pragma unroll
        for (int mi = 0; mi < 4; ++mi)
            #pragma unroll
            for (int ni = 0; ni < 2; ++ni) {
                acc[mi][ni] = __builtin_amdgcn_mfma_f32_16x16x32_bf16(
                    af[mi][0], bfr[ni][0], acc[mi][ni], 0, 0, 0);
                acc[mi][ni] = __builtin_amdgcn_mfma_f32_16x16x32_bf16(
                    af[mi][1], bfr[ni][1], acc[mi][ni], 0, 0, 0);
            }
    }
    #pragma unroll
    for (int mi = 0; mi < 4; ++mi)
        #pragma unroll
        for (int r = 0; r < 4; ++r) {
            int o = m0 + wm * 64 + mi * 16 + q * 4 + r;
            float bv = bias[o];
            #pragma unroll
            for (int ni = 0; ni < 2; ++ni) {
                int n = n0 + wn * 32 + ni * 16 + u;
                int b = n >> 11, t = n & 2047;
                size_t oi = ((size_t)b * C_DIM + o) * T_DIM + t;
                out[oi] = acc[mi][ni][r] + bv + xres[oi];
            }
        }
}

// ---------------------------------------------------------------------------
extern "C" void kernel_launch(void* const* d_in, const int* in_sizes, int n_in,
                              void* d_out, int out_size, void* d_ws, size_t ws_size,
                              hipStream_t stream)
{
    const float* x      = (const float*)d_in[0];
    const float* qkv_w  = (const float*)d_in[1];
    const float* qkv_b  = (const float*)d_in[2];
    const float* proj_w = (const float*)d_in[3];
    const float* proj_b = (const float*)d_in[4];
    float* out = (float*)d_out;

    char* ws = (char*)d_ws;
    ushortT* xb   = (ushortT*)(ws);                 //  8.39 MB  [8192][512]
    ushortT* wqb  = (ushortT*)(ws +  8388608);      //  1.57 MB  [1536][512]
    ushortT* wpb  = (ushortT*)(ws +  9961472);      //  0.52 MB  [512][512]
    ushortT* qkvT = (ushortT*)(ws + 10485760);      // 25.17 MB  [8192][1536] (V third unused)
    ushortT* Vn   = (ushortT*)(ws + 35651584);      //  8.45 MB  [4][8][64][VN_STRIDE]
    ushortT* AO   = (ushortT*)(ws + 44105728);      //  8.39 MB  [8192][512]

    prep     <<<2048, 256, 0, stream>>>(x, qkv_w, proj_w, xb, wqb, wpb);
    gemm_qkv <<<dim3(64, 12),   256, 0, stream>>>(xb, wqb, qkv_b, qkvT, Vn);
    flash    <<<512,            256, 0, stream>>>(qkvT, Vn, AO);
    gemm_proj<<<dim3(128, 4),   256, 0, stream>>>(wpb, AO, proj_b, x, out);
}

// Round 16
// 149.637 us; speedup vs baseline: 1.0212x; 1.0212x over previous
//
#include <hip/hip_runtime.h>
#include <hip/hip_bf16.h>
#include <math.h>

#define B_DIM 4
#define C_DIM 512
#define T_DIM 2048
#define H_DIM 8
#define OC3   1536
#define VN_STRIDE 2064   // R8-measured-best (R10 de-alias experiment regressed)
#define SCALE 0.044194173824159216f   // 512^-0.5 (full C, per reference)
#define SCALE2 (0.044194173824159216f * 1.4426950408889634f)   // fold log2(e)

typedef unsigned short ushortT;
typedef unsigned int uintT;
typedef __attribute__((ext_vector_type(8))) short bf16x8;
typedef __attribute__((ext_vector_type(4))) short bf16x4;
typedef __attribute__((ext_vector_type(4))) float f32x4;

__device__ __forceinline__ ushortT f2bf(float f) {
    union { float f; uintT u; } v; v.f = f;
    uintT r = v.u + 0x7FFF + ((v.u >> 16) & 1);   // RNE
    return (ushortT)(r >> 16);
}
__device__ __forceinline__ float bf2f(ushortT h) {
    union { uintT u; float f; } v; v.u = ((uintT)h) << 16;
    return v.f;
}
__device__ __forceinline__ uintT pack2bf(float a, float b) {
    uintT ua = __float_as_uint(a) + 0x8000u;
    uintT ub = __float_as_uint(b) + 0x8000u;
    return (ua >> 16) | (ub & 0xFFFF0000u);
}
// native pair conversion: compiler lowers adjacent __bf16 casts to
// v_cvt_pk_bf16_f32 on gfx950 (per m240: prefer casts over inline asm)
__device__ __forceinline__ uintT cvtpk2bf(float a, float b) {
    union { __bf16 v[2]; uintT u; } c;
    c.v[0] = (__bf16)a; c.v[1] = (__bf16)b;
    return c.u;
}
// async global->LDS, 16B per lane; lds base must be wave-uniform (data lands
// at base + lane*16) [m97/m104]
__device__ __forceinline__ void gload_lds16(const ushortT* g, ushortT* l) {
    __builtin_amdgcn_global_load_lds(
        (const __attribute__((address_space(1))) void*)g,
        (__attribute__((address_space(3))) void*)l, 16, 0, 0);
}

// ---------------------------------------------------------------------------
// prep: fused conv_x (blocks 0..1023) + conv_w (blocks 1024..2047).
// ---------------------------------------------------------------------------
__global__ __launch_bounds__(256) void prep(const float* __restrict__ x,
                                            const float* __restrict__ qw,
                                            const float* __restrict__ pw,
                                            ushortT* __restrict__ xb,
                                            ushortT* __restrict__ qwb,
                                            ushortT* __restrict__ pwb) {
    __shared__ float xs[64][65];
    const int tid = threadIdx.x;
    const int blk = blockIdx.x;
    if (blk >= 1024) {
        int idx = ((blk - 1024) * 256 + tid) * 4;
        if (idx < OC3 * C_DIM) {
            float4 v = *(const float4*)(qw + idx);
            qwb[idx + 0] = f2bf(v.x); qwb[idx + 1] = f2bf(v.y);
            qwb[idx + 2] = f2bf(v.z); qwb[idx + 3] = f2bf(v.w);
        } else {
            idx -= OC3 * C_DIM;
            float4 v = *(const float4*)(pw + idx);
            pwb[idx + 0] = f2bf(v.x); pwb[idx + 1] = f2bf(v.y);
            pwb[idx + 2] = f2bf(v.z); pwb[idx + 3] = f2bf(v.w);
        }
        return;
    }
    const int b = blk >> 8, rem = blk & 255;
    const int c0 = (rem >> 5) * 64, t0 = (rem & 31) * 64;
    #pragma unroll
    for (int it = 0; it < 4; ++it) {
        int idx = it * 256 + tid;
        int r = idx >> 4, ch = idx & 15;
        float4 v = *(const float4*)(x + ((size_t)(b * C_DIM + c0 + r)) * T_DIM + t0 + ch * 4);
        xs[r][ch * 4 + 0] = v.x; xs[r][ch * 4 + 1] = v.y;
        xs[r][ch * 4 + 2] = v.z; xs[r][ch * 4 + 3] = v.w;
    }
    __syncthreads();
    #pragma unroll
    for (int it = 0; it < 2; ++it) {
        int idx = it * 256 + tid;
        int rt = idx >> 3, ch = idx & 7;
        union { ushortT s[8]; uint4 v; } tmp;
        #pragma unroll
        for (int k = 0; k < 8; ++k) tmp.s[k] = f2bf(xs[ch * 8 + k][rt]);
        *(uint4*)(xb + ((size_t)b * T_DIM + t0 + rt) * C_DIM + c0 + ch * 8) = tmp.v;
    }
}

// ---------------------------------------------------------------------------
// QKV GEMM. R18 exact (verified best). Dispatch order already shares the
// B-panel across 64 consecutive blocks; R23's XCD swizzle regressed.
// ---------------------------------------------------------------------------
__global__ __launch_bounds__(256, 3) void gemm_qkv(const ushortT* __restrict__ A,
                                                   const ushortT* __restrict__ Bw,
                                                   const float* __restrict__ bias,
                                                   ushortT* __restrict__ out,
                                                   ushortT* __restrict__ Vn) {
    __shared__ __align__(16) ushortT As[8192], Bs[8192];   // 2 x [128][32] linear
    const int tid = threadIdx.x, lane = tid & 63, wid = tid >> 6;
    const int u = lane & 15, q = lane >> 4;
    const int wm = wid & 1, wn = wid >> 1;
    const int m0 = blockIdx.x * 128, n0 = blockIdx.y * 128;
    const int lrow = lane >> 2, lcol = (lane & 3) * 8;

    f32x4 acc[4][4];
    const f32x4 z = {0.f, 0.f, 0.f, 0.f};
    #pragma unroll
    for (int mi = 0; mi < 4; ++mi)
        #pragma unroll
        for (int ni = 0; ni < 4; ++ni) acc[mi][ni] = z;

    for (int k0 = 0; k0 < 512; k0 += 64) {
        __syncthreads();   // prior reads done before overwrite
        gload_lds16(A  + (size_t)(m0 + wid * 32 +      lrow) * 512 + k0      + lcol, &As[(wid * 32     ) * 32]);
        gload_lds16(A  + (size_t)(m0 + wid * 32 + 16 + lrow) * 512 + k0      + lcol, &As[(wid * 32 + 16) * 32]);
        gload_lds16(A  + (size_t)(m0 + wid * 32 +      lrow) * 512 + k0 + 32 + lcol, &As[4096 + (wid * 32     ) * 32]);
        gload_lds16(A  + (size_t)(m0 + wid * 32 + 16 + lrow) * 512 + k0 + 32 + lcol, &As[4096 + (wid * 32 + 16) * 32]);
        gload_lds16(Bw + (size_t)(n0 + wid * 32 +      lrow) * 512 + k0      + lcol, &Bs[(wid * 32     ) * 32]);
        gload_lds16(Bw + (size_t)(n0 + wid * 32 + 16 + lrow) * 512 + k0      + lcol, &Bs[(wid * 32 + 16) * 32]);
        gload_lds16(Bw + (size_t)(n0 + wid * 32 +      lrow) * 512 + k0 + 32 + lcol, &Bs[4096 + (wid * 32     ) * 32]);
        gload_lds16(Bw + (size_t)(n0 + wid * 32 + 16 + lrow) * 512 + k0 + 32 + lcol, &Bs[4096 + (wid * 32 + 16) * 32]);
        __syncthreads();   // vmcnt drained by barrier -> data visible
        bf16x8 af[4][2], bfr[4][2];
        #pragma unroll
        for (int mi = 0; mi < 4; ++mi) {
            af[mi][0] = *(const bf16x8*)&As[(wm * 64 + mi * 16 + u) * 32 + q * 8];
            af[mi][1] = *(const bf16x8*)&As[4096 + (wm * 64 + mi * 16 + u) * 32 + q * 8];
        }
        #pragma unroll
        for (int ni = 0; ni < 4; ++ni) {
            bfr[ni][0] = *(const bf16x8*)&Bs[(wn * 64 + ni * 16 + u) * 32 + q * 8];
            bfr[ni][1] = *(const bf16x8*)&Bs[4096 + (wn * 64 + ni * 16 + u) * 32 + q * 8];
        }
        #pragma unroll
        for (int mi = 0; mi < 4; ++mi)
            #pragma unroll
            for (int ni = 0; ni < 4; ++ni) {
                acc[mi][ni] = __builtin_amdgcn_mfma_f32_16x16x32_bf16(
                    af[mi][0], bfr[ni][0], acc[mi][ni], 0, 0, 0);
                acc[mi][ni] = __builtin_amdgcn_mfma_f32_16x16x32_bf16(
                    af[mi][1], bfr[ni][1], acc[mi][ni], 0, 0, 0);
            }
    }
    if (n0 < 1024) {   // Q or K region -> qkvT natural [m][o]
        const float scl = (n0 < 512) ? SCALE2 : 1.0f;
        #pragma unroll
        for (int ni = 0; ni < 4; ++ni) {
            int o = n0 + wn * 64 + ni * 16 + u;
            float bv = bias[o];
            #pragma unroll
            for (int mi = 0; mi < 4; ++mi)
                #pragma unroll
                for (int r = 0; r < 4; ++r) {
                    int m = m0 + wm * 64 + mi * 16 + q * 4 + r;
                    out[(size_t)m * OC3 + o] = f2bf((acc[mi][ni][r] + bv) * scl);
                }
        }
    } else {           // V region -> Vn[b][h][d][t] (transposed), packed 8B
        #pragma unroll
        for (int ni = 0; ni < 4; ++ni) {
            int o = n0 + wn * 64 + ni * 16 + u;
            float bv = bias[o];
            int oo = o - 1024;
            int hv = oo >> 6, d = oo & 63;
            #pragma unroll
            for (int mi = 0; mi < 4; ++mi) {
                int m = m0 + wm * 64 + mi * 16 + q * 4;
                int b = m >> 11, t = m & 2047;
                uint2 w;
                w.x = pack2bf(acc[mi][ni][0] + bv, acc[mi][ni][1] + bv);
                w.y = pack2bf(acc[mi][ni][2] + bv, acc[mi][ni][3] + bv);
                *(uint2*)(Vn + ((size_t)((b * 8 + hv) * 64 + d)) * VN_STRIDE + t) = w;
            }
        }
    }
}

// ---------------------------------------------------------------------------
// Flash attention: R24 exact (measured 51.8 us; total 150.25) = R15 structure
// + T5 setprio(1) around the MFMA cluster ONLY. R25 (setprio widened to
// cover the LDS fragment reads) REGRESSED to 54.9 (VGPR 84->64: compiler
// stopped interleaving fragment loads with prior-round compute). Placement
// is load-bearing -- do not move.
// CLOSED dead ends (do not retry): R11/R19/R21 occupancy-raising variants
// (spill / LDS-read amplification / spill), R12 manual K-dbuf, R16 small
// blocks, R17 gemm dbuf, R20 counted-vmcnt (drain is not the cost),
// R25 widened setprio.
// ---------------------------------------------------------------------------
__global__ __launch_bounds__(256, 2)
void flash(const ushortT* __restrict__ qkvT, const ushortT* __restrict__ Vn,
           ushortT* __restrict__ AO)
{
    __shared__ __align__(16) ushortT smem[16384];   // K dbuf 2x8KB | V dbuf 2x8KB

    const int tid = threadIdx.x, lane = tid & 63, wid = tid >> 6;
    const int u = lane & 15, q = lane >> 4;
    const int g = blockIdx.x;
    const int bh = (g & 7) * 4 + ((g >> 3) & 3);   // 4 bh per XCD -> KV L2-resident
    const int qt = g >> 5;                         // 16 q-tiles per bh share L2 KV
    const int bb = bh >> 3, h = bh & 7;
    const int q0 = qt * 128;
    const size_t qbase = (size_t)bb * T_DIM * OC3;

    // Q: 32 rows per wave (2 sub-tiles of 16), register-resident
    bf16x8 qb[2][2];
    #pragma unroll
    for (int ti = 0; ti < 2; ++ti)
        #pragma unroll
        for (int kst = 0; kst < 2; ++kst)
            qb[ti][kst] = *(const bf16x8*)(qkvT + qbase
                + (size_t)(q0 + wid * 32 + ti * 16 + u) * OC3 + h * 64 + kst * 32 + q * 8);

    // staging source pointers: lane stages 16B that lands (linearly) at LDS
    // row rs, slot (lane&7); source column slot pre-swizzled: sg = s ^ (rs&7)
    const int rs = wid * 8 + (lane >> 3);            // tile row 0..31 (call0)
    const int sg = (lane & 7) ^ (rs & 7);            // (rs+32)&7 == rs&7
    const ushortT* ks0 = qkvT + qbase + (size_t)(rs     ) * OC3 + 512 + h * 64 + sg * 8;
    const ushortT* ks1 = qkvT + qbase + (size_t)(rs + 32) * OC3 + 512 + h * 64 + sg * 8;
    const ushortT* vs0 = Vn + ((size_t)bh * 64 + rs     ) * VN_STRIDE + sg * 8;
    const ushortT* vs1 = Vn + ((size_t)bh * 64 + rs + 32) * VN_STRIDE + sg * 8;

    f32x4 acc[4][2];
    const f32x4 z = {0.f, 0.f, 0.f, 0.f};
    #pragma unroll
    for (int ci = 0; ci < 4; ++ci)
        #pragma unroll
        for (int ti = 0; ti < 2; ++ti) acc[ci][ti] = z;
    f32x4 lacc[2] = {z, z};
    const bf16x4 ones = {(short)0x3F80, (short)0x3F80, (short)0x3F80, (short)0x3F80};

    // prologue: stage tile 0 into buf 0
    gload_lds16(ks0, &smem[       wid * 512]);
    gload_lds16(ks1, &smem[2048 + wid * 512]);
    gload_lds16(vs0, &smem[8192 +        wid * 512]);
    gload_lds16(vs1, &smem[8192 + 2048 + wid * 512]);
    ks0 += 64 * OC3; ks1 += 64 * OC3; vs0 += 64; vs1 += 64;
    __syncthreads();   // compiler drains vmcnt before barrier

    int cur = 0;
    for (int rnd = 0; rnd < 32; ++rnd) {
        if (rnd < 31) {   // prefetch next tile into other buffer (async)
            int nb = cur ^ 1;
            gload_lds16(ks0, &smem[nb * 4096 +        wid * 512]);
            gload_lds16(ks1, &smem[nb * 4096 + 2048 + wid * 512]);
            gload_lds16(vs0, &smem[8192 + nb * 4096 +        wid * 512]);
            gload_lds16(vs1, &smem[8192 + nb * 4096 + 2048 + wid * 512]);
            ks0 += 64 * OC3; ks1 += 64 * OC3; vs0 += 64; vs1 += 64;
        }
        const ushortT* Kb = &smem[cur * 4096];
        const ushortT* Vb = &smem[8192 + cur * 4096];
        bf16x8 ka[4][2];
        #pragma unroll
        for (int si = 0; si < 4; ++si)
            #pragma unroll
            for (int kst = 0; kst < 2; ++kst)
                ka[si][kst] = *(const bf16x8*)&Kb[(si * 16 + u) * 64
                    + (((kst * 4 + q) ^ (u & 7)) * 8)];
        bf16x4 va[4][4];
        #pragma unroll
        for (int si = 0; si < 4; ++si)
            #pragma unroll
            for (int ci = 0; ci < 4; ++ci)
                va[si][ci] = *(const bf16x4*)&Vb[(ci * 16 + u) * 64
                    + (((si * 2 + (q >> 1)) ^ (u & 7)) * 8) + (q & 1) * 4];

        __builtin_amdgcn_s_setprio(1);   // T5: favor this wave's MFMA phase
        #pragma unroll
        for (int si = 0; si < 4; ++si) {
            f32x4 sacc[2] = {z, z};
            #pragma unroll
            for (int ti = 0; ti < 2; ++ti)
                sacc[ti] = __builtin_amdgcn_mfma_f32_16x16x32_bf16(
                    ka[si][0], qb[ti][0], sacc[ti], 0, 0, 0);
            #pragma unroll
            for (int ti = 0; ti < 2; ++ti)
                sacc[ti] = __builtin_amdgcn_mfma_f32_16x16x32_bf16(
                    ka[si][1], qb[ti][1], sacc[ti], 0, 0, 0);
            #pragma unroll
            for (int ti = 0; ti < 2; ++ti) {
                float p0 = __builtin_amdgcn_exp2f(sacc[ti][0]);
                float p1 = __builtin_amdgcn_exp2f(sacc[ti][1]);
                float p2 = __builtin_amdgcn_exp2f(sacc[ti][2]);
                float p3 = __builtin_amdgcn_exp2f(sacc[ti][3]);
                union { uint2 u2; bf16x4 v; } pw;
                pw.u2.x = cvtpk2bf(p0, p1);
                pw.u2.y = cvtpk2bf(p2, p3);
                lacc[ti] = __builtin_amdgcn_mfma_f32_16x16x16bf16_1k(
                    ones, pw.v, lacc[ti], 0, 0, 0);
                #pragma unroll
                for (int ci = 0; ci < 4; ++ci)
                    acc[ci][ti] = __builtin_amdgcn_mfma_f32_16x16x16bf16_1k(
                        va[si][ci], pw.v, acc[ci][ti], 0, 0, 0);
            }
        }
        __builtin_amdgcn_s_setprio(0);
        __syncthreads();   // next buffer staged + all reads of cur done
        cur ^= 1;
    }

    // ---- epilogue: reuse smem (all waves past final barrier) ----
    // Ob per wave: [32 q][72 d-pad] bf16; Lb: 4x32 f32 at ushort 9216
    ushortT* Ob = smem + wid * 2304;
    float* Lb = (float*)(smem + 9216);
    if (q == 0) {
        Lb[wid * 32 + u]      = lacc[0][0];
        Lb[wid * 32 + 16 + u] = lacc[1][0];
    }
    #pragma unroll
    for (int ci = 0; ci < 4; ++ci)
        #pragma unroll
        for (int ti = 0; ti < 2; ++ti) {
            uint2 w;
            w.x = pack2bf(acc[ci][ti][0], acc[ci][ti][1]);
            w.y = pack2bf(acc[ci][ti][2], acc[ci][ti][3]);
            *(uint2*)&Ob[(ti * 16 + u) * 72 + ci * 16 + q * 4] = w;
        }
    __syncthreads();
    {
        const int row = tid >> 1, cs = (tid & 1) * 32;   // 128 rows x 2 halves
        const int w = row >> 5, r32 = row & 31;
        float linv = 1.0f / Lb[w * 32 + r32];
        const ushortT* rp = smem + w * 2304 + r32 * 72 + cs;
        size_t orow = ((size_t)bb * T_DIM + q0 + row) * C_DIM + h * 64 + cs;
        #pragma unroll
        for (int j = 0; j < 4; ++j) {
            uint4 rv = *(const uint4*)(rp + j * 8);
            const uintT* rpp = (const uintT*)&rv;
            uint4 o;
            uintT* op = (uintT*)&o;
            #pragma unroll
            for (int k = 0; k < 4; ++k)
                op[k] = pack2bf(bf2f((ushortT)(rpp[k] & 0xFFFF)) * linv,
                                bf2f((ushortT)(rpp[k] >> 16)) * linv);
            *(uint4*)(AO + orow + j * 8) = o;
        }
    }
}

// ---------------------------------------------------------------------------
// Proj GEMM. R18 exact (verified best): 2-barrier, BN=64 -> grid 512 = 2/CU.
// out = Wp·AO^T + bias + x (fp32 out).
// ---------------------------------------------------------------------------
__global__ __launch_bounds__(256, 2) void gemm_proj(const ushortT* __restrict__ Wp,
                                                    const ushortT* __restrict__ AOv,
                                                    const float* __restrict__ bias,
                                                    const float* __restrict__ xres,
                                                    float* __restrict__ out) {
    __shared__ __align__(16) ushortT As[8192], Bs[4096];   // A: 2x[128][32]; B: 2x[64][32]
    const int tid = threadIdx.x, lane = tid & 63, wid = tid >> 6;
    const int u = lane & 15, q = lane >> 4;
    const int wm = wid & 1, wn = wid >> 1;
    const int m0 = blockIdx.y * 128, n0 = blockIdx.x * 64;
    const int lrow = lane >> 2, lcol = (lane & 3) * 8;

    f32x4 acc[4][2];
    const f32x4 z = {0.f, 0.f, 0.f, 0.f};
    #pragma unroll
    for (int mi = 0; mi < 4; ++mi)
        #pragma unroll
        for (int ni = 0; ni < 2; ++ni) acc[mi][ni] = z;

    for (int k0 = 0; k0 < 512; k0 += 64) {
        __syncthreads();
        gload_lds16(Wp  + (size_t)(m0 + wid * 32 +      lrow) * 512 + k0      + lcol, &As[(wid * 32     ) * 32]);
        gload_lds16(Wp  + (size_t)(m0 + wid * 32 + 16 + lrow) * 512 + k0      + lcol, &As[(wid * 32 + 16) * 32]);
        gload_lds16(Wp  + (size_t)(m0 + wid * 32 +      lrow) * 512 + k0 + 32 + lcol, &As[4096 + (wid * 32     ) * 32]);
        gload_lds16(Wp  + (size_t)(m0 + wid * 32 + 16 + lrow) * 512 + k0 + 32 + lcol, &As[4096 + (wid * 32 + 16) * 32]);
        gload_lds16(AOv + (size_t)(n0 + wid * 16 + lrow) * 512 + k0      + lcol, &Bs[(wid * 16) * 32]);
        gload_lds16(AOv + (size_t)(n0 + wid * 16 + lrow) * 512 + k0 + 32 + lcol, &Bs[2048 + (wid * 16) * 32]);
        __syncthreads();
        bf16x8 af[4][2], bfr[2][2];
        #pragma unroll
        for (int mi = 0; mi < 4; ++mi) {
            af[mi][0] = *(const bf16x8*)&As[(wm * 64 + mi * 16 + u) * 32 + q * 8];
            af[mi][1] = *(const bf16x8*)&As[4096 + (wm * 64 + mi * 16 + u) * 32 + q * 8];
        }
        #pragma unroll
        for (int ni = 0; ni < 2; ++ni) {
            bfr[ni][0] = *(const bf16x8*)&Bs[(wn * 32 + ni * 16 + u) * 32 + q * 8];
            bfr[ni][1] = *(const bf16x8*)&Bs[2048 + (wn * 32 + ni * 16 + u) * 32 + q * 8];
        }
        #pragma unroll
        for (int mi = 0; mi < 4; ++mi)
            #pragma unroll
            for (int ni = 0; ni < 2; ++ni) {
                acc[mi][ni] = __builtin_amdgcn_mfma_f32_16x16x32_bf16(
                    af[mi][0], bfr[ni][0], acc[mi][ni], 0, 0, 0);
                acc[mi][ni] = __builtin_amdgcn_mfma_f32_16x16x32_bf16(
                    af[mi][1], bfr[ni][1], acc[mi][ni], 0, 0, 0);
            }
    }
    #pragma unroll
    for (int mi = 0; mi < 4; ++mi)
        #pragma unroll
        for (int r = 0; r < 4; ++r) {
            int o = m0 + wm * 64 + mi * 16 + q * 4 + r;
            float bv = bias[o];
            #pragma unroll
            for (int ni = 0; ni < 2; ++ni) {
                int n = n0 + wn * 32 + ni * 16 + u;
                int b = n >> 11, t = n & 2047;
                size_t oi = ((size_t)b * C_DIM + o) * T_DIM + t;
                out[oi] = acc[mi][ni][r] + bv + xres[oi];
            }
        }
}

// ---------------------------------------------------------------------------
extern "C" void kernel_launch(void* const* d_in, const int* in_sizes, int n_in,
                              void* d_out, int out_size, void* d_ws, size_t ws_size,
                              hipStream_t stream)
{
    const float* x      = (const float*)d_in[0];
    const float* qkv_w  = (const float*)d_in[1];
    const float* qkv_b  = (const float*)d_in[2];
    const float* proj_w = (const float*)d_in[3];
    const float* proj_b = (const float*)d_in[4];
    float* out = (float*)d_out;

    char* ws = (char*)d_ws;
    ushortT* xb   = (ushortT*)(ws);                 //  8.39 MB  [8192][512]
    ushortT* wqb  = (ushortT*)(ws +  8388608);      //  1.57 MB  [1536][512]
    ushortT* wpb  = (ushortT*)(ws +  9961472);      //  0.52 MB  [512][512]
    ushortT* qkvT = (ushortT*)(ws + 10485760);      // 25.17 MB  [8192][1536] (V third unused)
    ushortT* Vn   = (ushortT*)(ws + 35651584);      //  8.45 MB  [4][8][64][VN_STRIDE]
    ushortT* AO   = (ushortT*)(ws + 44105728);      //  8.39 MB  [8192][512]

    prep     <<<2048, 256, 0, stream>>>(x, qkv_w, proj_w, xb, wqb, wpb);
    gemm_qkv <<<dim3(64, 12),   256, 0, stream>>>(xb, wqb, qkv_b, qkvT, Vn);
    flash    <<<512,            256, 0, stream>>>(qkvT, Vn, AO);
    gemm_proj<<<dim3(128, 4),   256, 0, stream>>>(wpb, AO, proj_b, x, out);
}